// Round 6
// baseline (439.150 us; speedup 1.0000x reference)
//
#include <hip/hip_runtime.h>

// CRF Viterbi decode, B=256, T=512, C=128.
// Outputs (flat f32): viterbi [B,T], inputs copy [B,T,C], seq_len [B], trans copy [C,C].
//
// 512 thr/block (8 waves), 1 block/batch. Thread (ccur=tid>>2, g=tid&3), JP=32.
// Value-only max (v_pk_add_f32 + v_max3 tree + 2-stage quad DPP max);
// backpointer = 4x8 equality priority-encode chains -> u32 min -> 2-stage quad
// DPP min (exact first-max tie rule), pipelined into the next step's LDS shadow.
// Input copy folded into forward-loop stall cycles. Backpointers u8 in LDS.

#define BB 256
#define TT 512
#define CC 128
#define NTH 512
#define GR 4
#define JP 32
#define SPAD 40  // floats; g*40: banks {0,8,16,24}+c distinct; 160B is 16B-aligned

#define OFF_VIT 0
#define OFF_INP (BB * TT)                 // 131072
#define OFF_LEN (OFF_INP + BB * TT * CC)  // 16908288
#define OFF_TR (OFF_LEN + BB)             // 16908544

#define BP_BYTES ((TT - 1) * CC)      // 65408, 16B aligned
#define STATE_FLOATS (2 * GR * SPAD)  // 320
#define SMEM_BYTES (BP_BYTES + STATE_FLOATS * 4 + 16 * 4 + 16)

#define SIDX(c) ((((c) >> 5) * SPAD) + ((c) & 31))

typedef float v2f __attribute__((ext_vector_type(2)));

__device__ __forceinline__ v2f pkadd(v2f a, v2f b) {
  v2f d;
  asm("v_pk_add_f32 %0, %1, %2" : "=v"(d) : "v"(a), "v"(b));
  return d;
}
__device__ __forceinline__ v2f lo4(float4 q) { return (v2f){q.x, q.y}; }
__device__ __forceinline__ v2f hi4(float4 q) { return (v2f){q.z, q.w}; }

#define F3(a, b, c) fmaxf(fmaxf((a), (b)), (c))

template <int C>
__device__ __forceinline__ float dppmaxf(float v) {
  float o = __int_as_float(__builtin_amdgcn_update_dpp(0, __float_as_int(v), C, 0xF, 0xF, true));
  return fmaxf(v, o);
}
template <int C>
__device__ __forceinline__ unsigned dppminu(unsigned v) {
  unsigned o = (unsigned)__builtin_amdgcn_update_dpp(0, (int)v, C, 0xF, 0xF, true);
  return v < o ? v : o;
}
__device__ __forceinline__ unsigned uminu(unsigned a, unsigned b) { return a < b ? a : b; }

__device__ __forceinline__ void lexmax(float& v, int& i, float ov, int oi) {
  bool take = (ov > v) || (ov == v && oi < i);  // first-max: lowest index wins ties
  v = take ? ov : v;
  i = take ? oi : i;
}
template <int C>
__device__ __forceinline__ void bfly_dpp(float& v, int& i) {
  float ov = __int_as_float(__builtin_amdgcn_update_dpp(0, __float_as_int(v), C, 0xF, 0xF, true));
  int oi = __builtin_amdgcn_update_dpp(0, i, C, 0xF, 0xF, true);
  lexmax(v, i, ov, oi);
}
__device__ __forceinline__ void bfly6(float& v, int& i) {
  bfly_dpp<0xB1>(v, i);   // xor1
  bfly_dpp<0x4E>(v, i);   // xor2
  bfly_dpp<0x141>(v, i);  // row_half_mirror (8)
  bfly_dpp<0x140>(v, i);  // row_mirror (16)
  { float ov = __shfl_xor(v, 16); int oi = __shfl_xor(i, 16); lexmax(v, i, ov, oi); }
  { float ov = __shfl_xor(v, 32); int oi = __shfl_xor(i, 32); lexmax(v, i, ov, oi); }
}

// previous step's backpointer from shadow regs sp0..spF (v2f) + sm.
// 4 descending cndmask chains over disjoint index ranges -> min = first max.
#define DO_BP                                                                   \
  {                                                                             \
    unsigned iA = 255u, iB = 255u, iC = 255u, iD = 255u;                        \
    iA = (sp3.y == sm) ? 7u : iA;   iB = (sp7.y == sm) ? 15u : iB;              \
    iA = (sp3.x == sm) ? 6u : iA;   iB = (sp7.x == sm) ? 14u : iB;              \
    iA = (sp2.y == sm) ? 5u : iA;   iB = (sp6.y == sm) ? 13u : iB;              \
    iA = (sp2.x == sm) ? 4u : iA;   iB = (sp6.x == sm) ? 12u : iB;              \
    iA = (sp1.y == sm) ? 3u : iA;   iB = (sp5.y == sm) ? 11u : iB;              \
    iA = (sp1.x == sm) ? 2u : iA;   iB = (sp5.x == sm) ? 10u : iB;              \
    iA = (sp0.y == sm) ? 1u : iA;   iB = (sp4.y == sm) ? 9u : iB;               \
    iA = (sp0.x == sm) ? 0u : iA;   iB = (sp4.x == sm) ? 8u : iB;               \
    iC = (spB.y == sm) ? 23u : iC;  iD = (spF.y == sm) ? 31u : iD;              \
    iC = (spB.x == sm) ? 22u : iC;  iD = (spF.x == sm) ? 30u : iD;              \
    iC = (spA.y == sm) ? 21u : iC;  iD = (spE.y == sm) ? 29u : iD;              \
    iC = (spA.x == sm) ? 20u : iC;  iD = (spE.x == sm) ? 28u : iD;              \
    iC = (sp9.y == sm) ? 19u : iC;  iD = (spD.y == sm) ? 27u : iD;              \
    iC = (sp9.x == sm) ? 18u : iC;  iD = (spD.x == sm) ? 26u : iD;              \
    iC = (sp8.y == sm) ? 17u : iC;  iD = (spC.y == sm) ? 25u : iD;              \
    iC = (sp8.x == sm) ? 16u : iC;  iD = (spC.x == sm) ? 24u : iD;              \
    unsigned bi = uminu(uminu(iA, iB), uminu(iC, iD)) + gbase;                  \
    bi = dppminu<0xB1>(bi);                                                     \
    bi = dppminu<0x4E>(bi);                                                     \
    if (g0) *bpw = (unsigned char)bi;                                           \
    bpw += CC;                                                                  \
  }

// One DP step. ROFF/WOFF: compile-time LDS float offsets (buffer parity).
#define STEP(ROFF, WOFF, SH)                                                    \
  {                                                                             \
    const float4* rp_ = (const float4*)(state_s + (ROFF) + g * SPAD);           \
    float4 a0 = rp_[0], a1 = rp_[1], a2 = rp_[2], a3 = rp_[3];                  \
    float4 a4 = rp_[4], a5 = rp_[5], a6 = rp_[6], a7 = rp_[7];                  \
    float potB = 0.f;                                                           \
    if (g0) potB = rowp[ccur];                                                  \
    rowp = (rowp < rowLast) ? rowp + CC : rowp;                                 \
    if (SH) DO_BP                                                               \
    v2f p0 = pkadd(lo4(a0), trp[0]), p1 = pkadd(hi4(a0), trp[1]);               \
    v2f p2 = pkadd(lo4(a1), trp[2]), p3 = pkadd(hi4(a1), trp[3]);               \
    v2f p4 = pkadd(lo4(a2), trp[4]), p5 = pkadd(hi4(a2), trp[5]);               \
    v2f p6 = pkadd(lo4(a3), trp[6]), p7 = pkadd(hi4(a3), trp[7]);               \
    v2f p8 = pkadd(lo4(a4), trp[8]), p9 = pkadd(hi4(a4), trp[9]);               \
    v2f pA = pkadd(lo4(a5), trp[10]), pB = pkadd(hi4(a5), trp[11]);             \
    v2f pC = pkadd(lo4(a6), trp[12]), pD = pkadd(hi4(a6), trp[13]);             \
    v2f pE = pkadd(lo4(a7), trp[14]), pF = pkadd(hi4(a7), trp[15]);             \
    float m = fmaxf(                                                            \
        F3(F3(F3(p0.x, p0.y, p1.x), F3(p1.y, p2.x, p2.y), F3(p3.x, p3.y, p4.x)),\
           F3(F3(p4.y, p5.x, p5.y), F3(p6.x, p6.y, p7.x), F3(p7.y, p8.x, p8.y)),\
           F3(F3(p9.x, p9.y, pA.x), F3(pA.y, pB.x, pB.y), F3(pC.x, pC.y, pD.x))),\
        F3(fmaxf(pD.y, pE.x), fmaxf(pE.y, pF.x), pF.y));                        \
    m = dppmaxf<0xB1>(m);                                                       \
    m = dppmaxf<0x4E>(m);                                                       \
    if (g0) *(state_s + (WOFF) + wslot) = m + pot;                              \
    pot = potA; potA = potB;                                                    \
    sp0 = p0; sp1 = p1; sp2 = p2; sp3 = p3; sp4 = p4; sp5 = p5; sp6 = p6;       \
    sp7 = p7; sp8 = p8; sp9 = p9; spA = pA; spB = pB; spC = pC; spD = pD;       \
    spE = pE; spF = pF; sm = m;                                                 \
    asm volatile("s_waitcnt lgkmcnt(0)\n\ts_barrier" ::: "memory");             \
  }

__global__ __launch_bounds__(NTH, 1) void crf_viterbi(
    const float* __restrict__ inputs, const unsigned char* __restrict__ mask_bytes,
    const float* __restrict__ trans, float* __restrict__ out) {
  extern __shared__ unsigned char smem[];
  unsigned char* bp_s = smem;                  // [T-1][C] u8 backpointers
  float* state_s = (float*)(smem + BP_BYTES);  // [2][GR*SPAD] padded dbuf state
  int* wsum = (int*)(state_s + STATE_FLOATS);

  const int b = blockIdx.x;
  const int tid = threadIdx.x;
  const int lane = tid & 63;
  const int wave = tid >> 6;
  const int ccur = tid >> 2;  // 0..127
  const int g = tid & 3;      // cprev group (4 adjacent lanes per tag, quad-aligned)
  const bool g0 = (g == 0);
  const unsigned gbase = (unsigned)(g * JP);
  const int wslot = SIDX(ccur);

  // mask dtype detection: int32 (byte1 of elem0 == 0) vs bool/int8
  const int w4 = (mask_bytes[1] == 0) ? 4 : 1;
  {
    int mb = mask_bytes[(size_t)(b * TT + tid) * (size_t)w4] != 0;
    unsigned long long bal = __ballot(mb);
    if (lane == 0) wsum[wave] = __popcll(bal);
  }

  // transition fragment in registers: trp[k] = trans[g*32+2k .. +2k+1][ccur]
  v2f trp[16];
#pragma unroll
  for (int k = 0; k < 16; ++k) {
    trp[k].x = trans[(g * JP + 2 * k) * CC + ccur];
    trp[k].y = trans[(g * JP + 2 * k + 1) * CC + ccur];
  }

  const float* pin = inputs + (size_t)b * TT * CC;

  // init: state(0) = inputs[b,0,:] into buffer par=0
  if (tid < CC) state_s[SIDX(tid)] = pin[tid];
  __syncthreads();

  int L = 0;
#pragma unroll
  for (int i = 0; i < 8; ++i) L += wsum[i];  // L in [256, 512]

  // 2-deep pot prefetch (writer lanes only); L >= 256 so rows 1..3 exist
  float pot = 0.f, potA = 0.f;
  if (g0) {
    pot = pin[CC + ccur];       // row 1
    potA = pin[2 * CC + ccur];  // row 2
  }
  const float* rowp = pin + 3 * CC;                    // next prefetch row (t+2)
  const float* rowLast = pin + (size_t)(TT - 1) * CC;  // clamp (always in-bounds)

  // shadow regs (previous step's pair-sums + cluster max)
  v2f sp0{}, sp1{}, sp2{}, sp3{}, sp4{}, sp5{}, sp6{}, sp7{};
  v2f sp8{}, sp9{}, spA{}, spB{}, spC{}, spD{}, spE{}, spF{};
  float sm = 0.f;
  unsigned char* bpw = bp_s + ccur;  // bp row cursor (advances CC per DO_BP)

  // folded input copy (32 float4/thread = this batch's full 256 KB)
  const float4* src4 = (const float4*)pin;
  float4* dst4 = (float4*)(out + OFF_INP + (size_t)b * TT * CC);
  int cp = 0;
  float4 cpv{};

  // ---- forward DP ----
  STEP(0, GR * SPAD, 0);  // prime: t=1 (reads par0, writes par1, no shadow yet)
  int t = 2;
  for (; t + 1 < L; t += 2) {
    STEP(GR * SPAD, 0, 1);  // even t: read par1, write par0
    if (cp < 32) cpv = src4[cp * NTH + tid];  // copy-load (hides in stalls)
    STEP(0, GR * SPAD, 1);  // odd t+1: read par0, write par1
    if (cp < 32) { dst4[cp * NTH + tid] = cpv; ++cp; }  // store, 1 step later
  }
  if (t < L) STEP(GR * SPAD, 0, 1);  // leftover single step (L odd)
  DO_BP  // flush last step's backpointers
  asm volatile("s_waitcnt lgkmcnt(0)\n\ts_barrier" ::: "memory");

  // safety net (unreachable for L>=66): finish any remaining copy
  for (; cp < 32; ++cp) dst4[cp * NTH + tid] = src4[cp * NTH + tid];

  float* outv = out + OFF_VIT + b * TT;

  // --- epilogue: wave 0 = final argmax + backtrack; wave 1 = trans copy ---
  if (wave == 0) {
    const float* fs = state_s + ((L - 1) & 1) * (GR * SPAD);
    float v1 = fs[SIDX(lane)];
    int c2 = lane + 64;
    float v2 = fs[SIDX(c2)];
    float v;
    int idx;
    if (v2 > v1) { v = v2; idx = c2; } else { v = v1; idx = lane; }
    bfly6(v, idx);

    // tags for t >= L-1 all equal last_tag (identity backpointers past length)
    for (int t2 = L - 1 + lane; t2 < TT; t2 += 64) outv[t2] = (float)idx;
    if (lane == 0) {
      out[OFF_LEN + b] = (float)L;
      int cur = idx;
      for (int tt = L - 2; tt >= 0; --tt) {
        cur = bp_s[tt * CC + cur];
        outv[tt] = (float)cur;
      }
    }
  } else if (wave == 1) {
    out[OFF_TR + b * 64 + lane] = trans[b * 64 + lane];  // 64 floats/block
  }
}

extern "C" void kernel_launch(void* const* d_in, const int* in_sizes, int n_in,
                              void* d_out, int out_size, void* d_ws, size_t ws_size,
                              hipStream_t stream) {
  const float* inputs = (const float*)d_in[0];
  const unsigned char* mask = (const unsigned char*)d_in[1];
  const float* trans = (const float*)d_in[2];
  float* out = (float*)d_out;

  crf_viterbi<<<BB, NTH, SMEM_BYTES, stream>>>(inputs, mask, trans, out);
}